// Round 2
// baseline (85.298 us; speedup 1.0000x reference)
//
#include <hip/hip_runtime.h>
#include <cstdint>

// Problem constants (from reference)
#define DIMS   1100
#define NPOS   784          // 28*28
#define NLEV   256
#define BATCH  512
#define NW     25           // ceil(784/32) words of packed position bits
#define TROW   260          // padded t-extent per w-row (257 needed; 260 => 16B-aligned, stride%32==4)

// ---------------------------------------------------------------------------
// Prep kernel: derive per-dimension threshold t[d] (count of -1s in the
// thermometer column) and pack position_weight signs into bit words
// pbits[w][d] (bit j = P[32w+j, d] > 0).
// ---------------------------------------------------------------------------
__global__ __launch_bounds__(256) void prep_kernel(
    const float* __restrict__ pos, const float* __restrict__ val,
    int* __restrict__ t_arr, uint32_t* __restrict__ pbits)
{
    int job = blockIdx.x * 256 + threadIdx.x;
    if (job < DIMS) {
        int d = job;
        int cnt = 0;
        for (int l = 0; l < NLEV; ++l)
            cnt += (val[l * DIMS + d] < 0.0f) ? 1 : 0;
        t_arr[d] = cnt;          // V[l][d] == +1  iff  l >= t_arr[d]
    } else if (job < DIMS + NW * DIMS) {
        int j = job - DIMS;
        int w = j / DIMS;
        int d = j - w * DIMS;
        int n0 = w * 32;
        int nmax = NPOS - n0; if (nmax > 32) nmax = 32;
        uint32_t bits = 0;
        for (int i = 0; i < nmax; ++i)
            bits |= (pos[(n0 + i) * DIMS + d] > 0.0f ? 1u : 0u) << i;
        pbits[w * DIMS + d] = bits;
    }
}

// ---------------------------------------------------------------------------
// Encode kernel: one block per batch element.
//  1. scatter equality bits E[idx][w] into LDS (atomicOr)
//  2. segmented suffix-OR scan over t  ->  U[t][w] = bits_n[idx >= t]
//  3. per d: diff = sum_w popcount(pbits[w][d] ^ U[t(d)][w]);
//     out = (diff < 392) ? +1 : -1    (s = 784 - 2*diff; s>0 <=> diff<392)
// LDS layout transposed: U[w * TROW + t]  (t contiguous -> b128 scan, and the
// main-loop gather at consecutive t per lane is bank-conflict-free).
// ---------------------------------------------------------------------------
__global__ __launch_bounds__(256) void encode_kernel(
    const float* __restrict__ x, const int* __restrict__ t_arr,
    const uint32_t* __restrict__ pbits, float* __restrict__ out)
{
    __shared__ uint32_t U[NW * TROW];   // 25*260 words = 26 KB
    __shared__ uint32_t S[NW * 8];      // segment totals

    const int tid = threadIdx.x;
    const int b = blockIdx.x;

    // ---- zero U ----
    uint4* U4 = (uint4*)U;
    #pragma unroll
    for (int i = 0; i < (NW * TROW / 4 + 255) / 256; ++i) {
        int p = tid + i * 256;
        if (p < NW * TROW / 4) U4[p] = make_uint4(0u, 0u, 0u, 0u);
    }
    __syncthreads();

    // ---- scatter equality bits ----
    for (int n = tid; n < NPOS; n += 256) {
        float v = x[b * NPOS + n] * (1.0f / 256.0f);  // exact (pow2 scale)
        v = fminf(fmaxf(v, 0.0f), 1.0f) * 255.0f;
        int idx = (int)rintf(v);                      // round half to even, as jnp.round
        atomicOr(&U[(n >> 5) * TROW + idx], 1u << (n & 31));
    }
    __syncthreads();

    // ---- suffix-OR scan: U[t] = OR_{l>=t} E[l]; 25 w-cols x 8 segments of 32 ----
    const int w = tid & 31;
    const int seg = tid >> 5;            // 0..7
    if (w < NW) {
        uint4* row4 = (uint4*)&U[w * TROW + seg * 32];
        uint32_t rr[32];
        #pragma unroll
        for (int i = 0; i < 8; ++i) {
            uint4 t4 = row4[i];
            rr[4*i+0] = t4.x; rr[4*i+1] = t4.y; rr[4*i+2] = t4.z; rr[4*i+3] = t4.w;
        }
        uint32_t acc = 0;
        #pragma unroll
        for (int k = 31; k >= 0; --k) { acc |= rr[k]; rr[k] = acc; }
        #pragma unroll
        for (int i = 0; i < 8; ++i)
            row4[i] = make_uint4(rr[4*i+0], rr[4*i+1], rr[4*i+2], rr[4*i+3]);
        S[w * 8 + seg] = acc;
    }
    __syncthreads();
    if (w < NW) {
        uint32_t carry = 0;
        for (int s2 = seg + 1; s2 < 8; ++s2) carry |= S[w * 8 + s2];
        if (carry) {
            uint4* row4 = (uint4*)&U[w * TROW + seg * 32];
            #pragma unroll
            for (int i = 0; i < 8; ++i) {
                uint4 r = row4[i];
                r.x |= carry; r.y |= carry; r.z |= carry; r.w |= carry;
                row4[i] = r;
            }
        }
    }
    __syncthreads();

    // ---- main: each thread covers d = tid + 256k ----
    #pragma unroll
    for (int k = 0; k < 5; ++k) {
        int d = tid + (k << 8);
        if (d < DIMS) {
            int td = t_arr[d];
            uint32_t diff = 0;
            #pragma unroll
            for (int ww = 0; ww < NW; ++ww) {
                uint32_t pb = pbits[ww * DIMS + d];
                uint32_t ub = U[ww * TROW + td];
                diff += __popc(pb ^ ub);
            }
            out[b * DIMS + d] = (diff < (NPOS / 2)) ? 1.0f : -1.0f;
        }
    }
}

// ---------------------------------------------------------------------------
extern "C" void kernel_launch(void* const* d_in, const int* in_sizes, int n_in,
                              void* d_out, int out_size, void* d_ws, size_t ws_size,
                              hipStream_t stream) {
    const float* x   = (const float*)d_in[0];   // (512, 28, 28)
    const float* pos = (const float*)d_in[1];   // (784, 1100)
    const float* val = (const float*)d_in[2];   // (256, 1100)
    float* out = (float*)d_out;                 // (512, 1100) float32

    // workspace: t_arr[1100] ints, then pbits[25][1100] words (offset 1104 words, 16B aligned)
    int* t_arr = (int*)d_ws;
    uint32_t* pbits = (uint32_t*)d_ws + 1104;

    const int prep_jobs = DIMS + NW * DIMS;     // 28,600
    prep_kernel<<<(prep_jobs + 255) / 256, 256, 0, stream>>>(pos, val, t_arr, pbits);
    encode_kernel<<<BATCH, 256, 0, stream>>>(x, t_arr, pbits, out);
}

// Round 6
// 77.250 us; speedup vs baseline: 1.1042x; 1.1042x over previous
//
#include <hip/hip_runtime.h>
#include <cstdint>

// Problem constants (from reference)
#define DIMS   1100
#define NPOS   784          // 28*28
#define NLEV   256
#define BATCH  512
#define NW     25           // ceil(784/32) words of packed position bits
#define TROW   268          // padded words per w-row: 268%4==0 (16B aligned), 268%32==12 ->
                            // 8 consecutive w-rows start in 8 distinct bank groups

// ---------------------------------------------------------------------------
// Prep kernel (ballot version): one block per dimension d.
//   t_arr[d] = count of -1s in thermometer column d  (V[l][d]==+1 iff l>=t)
//   pbits[w][d] = packed sign bits of position_weight column d
// Each thread does exactly 1 val load + up to 4 predicated pos loads; sign
// bits are gathered with __ballot (64-wide) -> no serial load chains.
// ---------------------------------------------------------------------------
__global__ __launch_bounds__(256) void prep2_kernel(
    const float* __restrict__ pos, const float* __restrict__ val,
    int* __restrict__ t_arr, uint32_t* __restrict__ pbits)
{
    const int d    = blockIdx.x;       // 0..1099
    const int tid  = threadIdx.x;      // 0..255
    const int lane = tid & 63;
    const int wv   = tid >> 6;         // wave id 0..3
    __shared__ int s4[4];

    // ---- t_arr: level l = tid (exactly 256 levels) ----
    bool neg = val[tid * DIMS + d] < 0.0f;
    unsigned long long m = __ballot(neg);
    if (lane == 0) s4[wv] = __popcll(m);

    // ---- pbits: 4 passes over n = p*256 + tid ----
    #pragma unroll
    for (int p = 0; p < 4; ++p) {
        int n = p * 256 + tid;
        bool bit = (n < NPOS) ? (pos[n * DIMS + d] > 0.0f) : false;
        unsigned long long mm = __ballot(bit);
        int w0 = p * 8 + wv * 2;       // word covered by this wave's low half
        if (lane == 0 && w0 < NW)      pbits[w0 * DIMS + d]       = (uint32_t)mm;
        if (lane == 32 && w0 + 1 < NW) pbits[(w0 + 1) * DIMS + d] = (uint32_t)(mm >> 32);
    }

    __syncthreads();
    if (tid == 0) t_arr[d] = s4[0] + s4[1] + s4[2] + s4[3];
}

// ---------------------------------------------------------------------------
// Encode kernel: one block per batch element.
//  1. scatter equality bits E[idx][w] into LDS (atomicOr)
//  2. segmented suffix-OR scan over t  ->  U[t][w] = bits_n[idx >= t]
//     (streaming reverse RMW: live set ~5 regs, no spill risk)
//  3. per d: diff = sum_w popcount(pbits[w][d] ^ U[t(d)][w]);
//     out = (diff < 392) ? +1 : -1    (s = 784 - 2*diff; s>0 <=> diff<392)
// ---------------------------------------------------------------------------
__global__ __launch_bounds__(256) void encode_kernel(
    const float* __restrict__ x, const int* __restrict__ t_arr,
    const uint32_t* __restrict__ pbits, float* __restrict__ out)
{
    __shared__ uint32_t U[NW * TROW];   // 25*268 words = 26.8 KB
    __shared__ uint32_t S[NW * 8];      // segment totals

    const int tid = threadIdx.x;
    const int b = blockIdx.x;

    // ---- prefetch thresholds early (hides global latency under LDS phases) ----
    int td0[5];
    #pragma unroll
    for (int k = 0; k < 5; ++k) {
        int d = tid + (k << 8);
        td0[k] = (d < DIMS) ? t_arr[d] : 0;
    }

    // ---- zero U ----
    uint4* U4 = (uint4*)U;
    #pragma unroll
    for (int i = 0; i < 7; ++i) {            // 7*256 = 1792 >= 25*268/4 = 1675
        int p = tid + i * 256;
        if (p < NW * TROW / 4) U4[p] = make_uint4(0u, 0u, 0u, 0u);
    }
    __syncthreads();

    // ---- scatter equality bits (x as float4: 196 threads x 4 pixels) ----
    if (tid < NPOS / 4) {
        float4 xv = ((const float4*)x)[b * (NPOS / 4) + tid];
        float vv[4] = {xv.x, xv.y, xv.z, xv.w};
        #pragma unroll
        for (int j = 0; j < 4; ++j) {
            int n = tid * 4 + j;
            float v = fminf(fmaxf(vv[j] * (1.0f / 256.0f), 0.0f), 1.0f) * 255.0f;
            int idx = (int)rintf(v);         // round half to even, as jnp.round
            atomicOr(&U[(n >> 5) * TROW + idx], 1u << (n & 31));
        }
    }
    __syncthreads();

    // ---- suffix-OR scan: U[t] = OR_{l>=t} E[l]; 25 w-rows x 8 segments of 32 ----
    if (tid < NW * 8) {
        const int w = tid >> 3, seg = tid & 7;
        uint4* row4 = (uint4*)&U[w * TROW + seg * 32];
        uint32_t acc = 0;
        #pragma unroll
        for (int i = 7; i >= 0; --i) {       // reverse streaming RMW, ~5 live regs
            uint4 t = row4[i];
            uint32_t d3 = acc | t.w, d2 = d3 | t.z, d1 = d2 | t.y, d0 = d1 | t.x;
            row4[i] = make_uint4(d0, d1, d2, d3);
            acc = d0;
        }
        S[tid] = acc;
    }
    __syncthreads();
    if (tid < NW * 8) {
        const int w = tid >> 3, seg = tid & 7;
        uint32_t carry = 0;
        for (int s2 = seg + 1; s2 < 8; ++s2) carry |= S[(w << 3) + s2];
        if (carry) {
            uint4* row4 = (uint4*)&U[w * TROW + seg * 32];
            #pragma unroll
            for (int i = 0; i < 8; ++i) {
                uint4 r = row4[i];
                row4[i] = make_uint4(r.x | carry, r.y | carry, r.z | carry, r.w | carry);
            }
        }
    }
    __syncthreads();

    // ---- main: each thread covers d = tid + 256k ----
    #pragma unroll
    for (int k = 0; k < 5; ++k) {
        int d = tid + (k << 8);
        if (d < DIMS) {
            int t = td0[k];
            uint32_t diff = 0;
            #pragma unroll
            for (int ww = 0; ww < NW; ++ww) {
                uint32_t pb = pbits[ww * DIMS + d];   // coalesced, L2-resident
                uint32_t ub = U[ww * TROW + t];
                diff += __popc(pb ^ ub);
            }
            out[b * DIMS + d] = (diff < (NPOS / 2)) ? 1.0f : -1.0f;
        }
    }
}

// ---------------------------------------------------------------------------
extern "C" void kernel_launch(void* const* d_in, const int* in_sizes, int n_in,
                              void* d_out, int out_size, void* d_ws, size_t ws_size,
                              hipStream_t stream) {
    const float* x   = (const float*)d_in[0];   // (512, 28, 28)
    const float* pos = (const float*)d_in[1];   // (784, 1100)
    const float* val = (const float*)d_in[2];   // (256, 1100)
    float* out = (float*)d_out;                 // (512, 1100) float32

    // workspace: t_arr[1100] ints, then pbits[25][1100] words (offset 1104 words, 16B aligned)
    int* t_arr = (int*)d_ws;
    uint32_t* pbits = (uint32_t*)d_ws + 1104;

    prep2_kernel<<<DIMS, 256, 0, stream>>>(pos, val, t_arr, pbits);
    encode_kernel<<<BATCH, 256, 0, stream>>>(x, t_arr, pbits, out);
}